// Round 1
// baseline (501.688 us; speedup 1.0000x reference)
//
#include <hip/hip_runtime.h>
#include <hip/hip_bf16.h>

// ---------------------------------------------------------------------------
// Fused XCiT-style channel attention, one batch item per 512-thread block.
// B=2048, N=49 (7x7), DIM=384, HEADS=8, HD=48.
// ---------------------------------------------------------------------------

typedef __attribute__((ext_vector_type(8))) short short8;   // 8 x bf16 (4 VGPR)
typedef __attribute__((ext_vector_type(4))) short short4v;  // 4 x bf16 (8B)
typedef __attribute__((ext_vector_type(4))) float f32x4;    // MFMA acc

#define NPOS   49
#define DIMC   384
#define SCALE_QK 0.14433756729740643f   // 48^-0.5

// LDS layout (bytes). Total 161296 <= 163840.
//  offA: X bf16 [49][392] (stride 784B) -> later reused as R (relu buffer)
//  offQ: Qt bf16 [384][56] (stride 112B)   } later overlaid by
//  offK: Kt bf16 [384][56]                 } Vn bf16 [64][408] (stride 816B) @ offQ
//  offE: E  bf16 [8][48][48] (row stride 96B)
#define offA 0
#define offQ 38416
#define offK 81424
#define offV 38416
#define offE 124432
#define LDS_BYTES 161296

__device__ __forceinline__ unsigned short f2bf(float f) {
  union { float f; unsigned u; } v; v.f = f;
  unsigned r = v.u + 0x7FFFu + ((v.u >> 16) & 1u);
  return (unsigned short)(r >> 16);
}
__device__ __forceinline__ float bf2f(unsigned short u) {
  union { unsigned u; float f; } v; v.u = ((unsigned)u) << 16;
  return v.f;
}

// ---- prologue: convert Wq,Wk,Wv,Wp (f32 [384][384]) to bf16 in d_ws --------
__global__ void wconv_kernel(const float* __restrict__ Wq, const float* __restrict__ Wk,
                             const float* __restrict__ Wv, const float* __restrict__ Wp,
                             unsigned short* __restrict__ dst) {
  int i = blockIdx.x * 256 + threadIdx.x;
  if (i >= 4 * 147456) return;
  const float* s; int o;
  if (i < 147456)      { s = Wq; o = i; }
  else if (i < 294912) { s = Wk; o = i - 147456; }
  else if (i < 442368) { s = Wv; o = i - 294912; }
  else                 { s = Wp; o = i - 442368; }
  dst[i] = f2bf(s[o]);
}

// ---- main fused kernel -----------------------------------------------------
__global__ __launch_bounds__(512, 2) void attn_fused_kernel(
    const float* __restrict__ x,
    const float* __restrict__ bq, const float* __restrict__ bk,
    const float* __restrict__ bv,
    const float* __restrict__ Wvl, const float* __restrict__ bvl,
    const float* __restrict__ Wth1, const float* __restrict__ bth1,
    const float* __restrict__ Wth2, const float* __restrict__ bth2,
    const float* __restrict__ bp,
    const unsigned short* __restrict__ Wbf,
    float* __restrict__ out) {
  extern __shared__ char smem[];
  const int tid = threadIdx.x;
  const int l   = tid & 63;
  const int w   = tid >> 6;          // wave 0..7
  const int lhi = l >> 4;            // 0..3
  const int llo = l & 15;
  const int b   = blockIdx.x;

  const float* xb = x + (size_t)b * (NPOS * DIMC);
  const unsigned short* Wq_bf = Wbf;
  const unsigned short* Wk_bf = Wbf + 147456;
  const unsigned short* Wv_bf = Wbf + 294912;
  const unsigned short* Wp_bf = Wbf + 442368;

  // ---- phase 0: stage x_b -> X bf16 [49][392] -------------------------------
  for (int idx = tid; idx < 49 * 48; idx += 512) {
    int row = idx / 48, c8 = idx % 48;
    const float4 v0 = *(const float4*)(xb + row * 384 + c8 * 8);
    const float4 v1 = *(const float4*)(xb + row * 384 + c8 * 8 + 4);
    short8 s;
    s[0] = (short)f2bf(v0.x); s[1] = (short)f2bf(v0.y);
    s[2] = (short)f2bf(v0.z); s[3] = (short)f2bf(v0.w);
    s[4] = (short)f2bf(v1.x); s[5] = (short)f2bf(v1.y);
    s[6] = (short)f2bf(v1.z); s[7] = (short)f2bf(v1.w);
    *(short8*)(smem + offA + row * 784 + c8 * 16) = s;
  }
  __syncthreads();

  // ---- phase 1: Q GEMM (waves 0-3) / K GEMM (waves 4-7), transposed store --
  {
    const int wq = w & 3;
    const unsigned short* Wg = (w < 4) ? Wq_bf : Wk_bf;
    const float* bg          = (w < 4) ? bq    : bk;
    char* dst = smem + ((w < 4) ? offQ : offK);
    f32x4 acc[4][6] = {};
    for (int ks = 0; ks < 12; ++ks) {
      short8 a[4];
      #pragma unroll
      for (int m = 0; m < 4; ++m) {
        int row = m * 16 + llo; row = (row > 48) ? 48 : row;   // M-pad clamp
        a[m] = *(const short8*)(smem + offA + row * 784 + ks * 64 + lhi * 16);
      }
      #pragma unroll
      for (int n = 0; n < 6; ++n) {
        const int o = (wq * 6 + n) * 16 + llo;
        short8 bfr = *(const short8*)(Wg + o * 384 + ks * 32 + lhi * 8);
        #pragma unroll
        for (int m = 0; m < 4; ++m)
          acc[m][n] = __builtin_amdgcn_mfma_f32_16x16x32_bf16(a[m], bfr, acc[m][n], 0, 0, 0);
      }
    }
    #pragma unroll
    for (int n = 0; n < 6; ++n) {
      const int o = (wq * 6 + n) * 16 + llo;
      const float bias = bg[o];
      #pragma unroll
      for (int m = 0; m < 4; ++m) {
        const int n0 = m * 16 + lhi * 4;          // position index of acc[..][0]
        if (n0 > 48) continue;
        unsigned short u0 = f2bf(acc[m][n][0] + bias);
        if (n0 == 48) {
          *(unsigned short*)(dst + o * 112 + n0 * 2) = u0;
        } else {
          short4v pk;
          pk[0] = (short)u0;
          pk[1] = (short)f2bf(acc[m][n][1] + bias);
          pk[2] = (short)f2bf(acc[m][n][2] + bias);
          pk[3] = (short)f2bf(acc[m][n][3] + bias);
          *(short4v*)(dst + o * 112 + n0 * 2) = pk;
        }
      }
    }
  }
  __syncthreads();

  // ---- phase 2: L2-normalize Qt/Kt rows over 49 positions; zero cols 49..55 -
  for (int idx = tid; idx < 768; idx += 512) {
    char* rp = smem + ((idx < 384) ? offQ : offK) + (idx & 383) * 112;
    short8 v[6];
    float ss = 0.f;
    #pragma unroll
    for (int i = 0; i < 6; ++i) {
      v[i] = *(short8*)(rp + i * 16);
      #pragma unroll
      for (int j = 0; j < 8; ++j) { float f = bf2f((unsigned short)v[i][j]); ss += f * f; }
    }
    float v48 = bf2f(*(unsigned short*)(rp + 96));
    ss += v48 * v48;
    float sc = 1.f / fmaxf(sqrtf(ss), 1e-12f);
    #pragma unroll
    for (int i = 0; i < 6; ++i) {
      short8 o8;
      #pragma unroll
      for (int j = 0; j < 8; ++j) o8[j] = (short)f2bf(bf2f((unsigned short)v[i][j]) * sc);
      *(short8*)(rp + i * 16) = o8;
    }
    short4v t; t[0] = (short)f2bf(v48 * sc); t[1] = 0; t[2] = 0; t[3] = 0;
    *(short4v*)(rp + 96) = t;
    short4v z = {0, 0, 0, 0};
    *(short4v*)(rp + 104) = z;
  }
  __syncthreads();

  // ---- phase 3: per-head gram G[c][d] = sum_n q~[c][n] k~[d][n] (head = w) --
  {
    const int h = w;
    f32x4 g[3][3] = {};
    #pragma unroll
    for (int ks = 0; ks < 2; ++ks) {
      short8 aq[3], bk8[3];
      #pragma unroll
      for (int m = 0; m < 3; ++m) {
        short8 t = {0,0,0,0,0,0,0,0};
        if (!(ks == 1 && lhi == 3))  // n=56..63 do not exist
          t = *(const short8*)(smem + offQ + (h * 48 + m * 16 + llo) * 112 + ks * 64 + lhi * 16);
        aq[m] = t;
      }
      #pragma unroll
      for (int n = 0; n < 3; ++n) {
        short8 t = {0,0,0,0,0,0,0,0};
        if (!(ks == 1 && lhi == 3))
          t = *(const short8*)(smem + offK + (h * 48 + n * 16 + llo) * 112 + ks * 64 + lhi * 16);
        bk8[n] = t;
      }
      #pragma unroll
      for (int m = 0; m < 3; ++m)
        #pragma unroll
        for (int n = 0; n < 3; ++n)
          g[m][n] = __builtin_amdgcn_mfma_f32_16x16x32_bf16(aq[m], bk8[n], g[m][n], 0, 0, 0);
    }
    #pragma unroll
    for (int m = 0; m < 3; ++m)
      #pragma unroll
      for (int n = 0; n < 3; ++n)
        #pragma unroll
        for (int r = 0; r < 4; ++r) {
          int c = m * 16 + lhi * 4 + r, d = n * 16 + llo;
          *(unsigned short*)(smem + offE + ((h * 48 + c) * 48 + d) * 2) = f2bf(g[m][n][r]);
        }
  }
  __syncthreads();

  // ---- phase 4: talking-heads mix1 (SCALE folded into W1), in-place on E ----
  {
    float w1[64], b1r[8];
    #pragma unroll
    for (int i = 0; i < 64; ++i) w1[i] = Wth1[i] * SCALE_QK;
    #pragma unroll
    for (int i = 0; i < 8; ++i) b1r[i] = bth1[i];
    for (int s = tid; s < 2304; s += 512) {
      char* base = smem + offE + s * 2;   // s = c*48+d
      float gg[8];
      #pragma unroll
      for (int hh = 0; hh < 8; ++hh) gg[hh] = bf2f(*(unsigned short*)(base + hh * 4608));
      #pragma unroll
      for (int gdx = 0; gdx < 8; ++gdx) {
        float t = b1r[gdx];
        #pragma unroll
        for (int hh = 0; hh < 8; ++hh) t += gg[hh] * w1[gdx * 8 + hh];
        *(unsigned short*)(base + gdx * 4608) = f2bf(t);
      }
    }
  }
  __syncthreads();

  // ---- phase 4b: row softmax over d (rows = (g,c), 384 of them) -------------
  for (int row = tid; row < 384; row += 512) {
    char* rp = smem + offE + row * 96;
    float vv[48];
    #pragma unroll
    for (int i = 0; i < 6; ++i) {
      short8 v8 = *(short8*)(rp + i * 16);
      #pragma unroll
      for (int j = 0; j < 8; ++j) vv[i * 8 + j] = bf2f((unsigned short)v8[j]);
    }
    float mx = vv[0];
    #pragma unroll
    for (int i = 1; i < 48; ++i) mx = fmaxf(mx, vv[i]);
    float sum = 0.f;
    #pragma unroll
    for (int i = 0; i < 48; ++i) { vv[i] = __expf(vv[i] - mx); sum += vv[i]; }
    float inv = 1.f / sum;
    #pragma unroll
    for (int i = 0; i < 6; ++i) {
      short8 o8;
      #pragma unroll
      for (int j = 0; j < 8; ++j) o8[j] = (short)f2bf(vv[i * 8 + j] * inv);
      *(short8*)(rp + i * 16) = o8;
    }
  }
  __syncthreads();

  // ---- phase 4c: talking-heads mix2, in-place on E --------------------------
  {
    float w2[64], b2r[8];
    #pragma unroll
    for (int i = 0; i < 64; ++i) w2[i] = Wth2[i];
    #pragma unroll
    for (int i = 0; i < 8; ++i) b2r[i] = bth2[i];
    for (int s = tid; s < 2304; s += 512) {
      char* base = smem + offE + s * 2;
      float gg[8];
      #pragma unroll
      for (int hh = 0; hh < 8; ++hh) gg[hh] = bf2f(*(unsigned short*)(base + hh * 4608));
      #pragma unroll
      for (int gdx = 0; gdx < 8; ++gdx) {
        float t = b2r[gdx];
        #pragma unroll
        for (int hh = 0; hh < 8; ++hh) t += gg[hh] * w2[gdx * 8 + hh];
        *(unsigned short*)(base + gdx * 4608) = f2bf(t);
      }
    }
  }
  __syncthreads();

  // ---- phase 5: V GEMM -> Vn natural [64][408] (overlays dead Qt/Kt) --------
  {
    f32x4 acc[4][3] = {};
    for (int ks = 0; ks < 12; ++ks) {
      short8 a[4];
      #pragma unroll
      for (int m = 0; m < 4; ++m) {
        int row = m * 16 + llo; row = (row > 48) ? 48 : row;
        a[m] = *(const short8*)(smem + offA + row * 784 + ks * 64 + lhi * 16);
      }
      #pragma unroll
      for (int n = 0; n < 3; ++n) {
        const int o = (w * 3 + n) * 16 + llo;
        short8 bfr = *(const short8*)(Wv_bf + o * 384 + ks * 32 + lhi * 8);
        #pragma unroll
        for (int m = 0; m < 4; ++m)
          acc[m][n] = __builtin_amdgcn_mfma_f32_16x16x32_bf16(a[m], bfr, acc[m][n], 0, 0, 0);
      }
    }
    #pragma unroll
    for (int n = 0; n < 3; ++n) {
      const int o = (w * 3 + n) * 16 + llo;
      const float bias = bv[o];
      #pragma unroll
      for (int m = 0; m < 4; ++m)
        #pragma unroll
        for (int r = 0; r < 4; ++r) {
          int np = m * 16 + lhi * 4 + r;
          if (np < 49)
            *(unsigned short*)(smem + offV + np * 816 + o * 2) = f2bf(acc[m][n][r] + bias);
        }
    }
    // zero pads: rows 49..63 (all 408 cols) and cols 384..407 (rows 0..48)
    for (int idx = tid; idx < 7296; idx += 512) {
      int row, col;
      if (idx < 6120) { row = 49 + idx / 408; col = idx % 408; }
      else            { int j2 = idx - 6120; row = j2 / 24; col = 384 + j2 % 24; }
      *(unsigned short*)(smem + offV + row * 816 + col * 2) = 0;
    }
  }
  __syncthreads();

  // ---- phase 6a: depthwise 3x3 + bvl -> R [49][392] (overlays dead X) -------
  for (int idx = tid; idx < 2352; idx += 512) {
    int n = idx / 48, c8 = idx % 48;
    int o0 = c8 * 8;
    int y = n / 7, xq = n % 7;
    float a[8];
    #pragma unroll
    for (int j = 0; j < 8; ++j) a[j] = bvl[o0 + j];
    #pragma unroll
    for (int dy = 0; dy < 3; ++dy) {
      int yy = y + dy - 1;
      if (yy < 0 || yy > 6) continue;
      #pragma unroll
      for (int dx = 0; dx < 3; ++dx) {
        int xx = xq + dx - 1;
        if (xx < 0 || xx > 6) continue;
        short8 vv = *(const short8*)(smem + offV + (yy * 7 + xx) * 816 + o0 * 2);
        const float* wp = Wvl + (dy * 3 + dx) * 384 + o0;
        #pragma unroll
        for (int j = 0; j < 8; ++j) a[j] += bf2f((unsigned short)vv[j]) * wp[j];
      }
    }
    short8 s8;
    #pragma unroll
    for (int j = 0; j < 8; ++j) s8[j] = (short)f2bf(a[j]);
    *(short8*)(smem + offA + n * 784 + c8 * 16) = s8;
  }
  __syncthreads();

  // ---- phase 6b: AV per head (head = w); RMW R with +v_local, fused ReLU ----
  {
    const int h = w;
    f32x4 oacc[3][4] = {};
    #pragma unroll
    for (int ks = 0; ks < 2; ++ks) {
      short8 af[3];
      #pragma unroll
      for (int m = 0; m < 3; ++m) {
        short8 t = {0,0,0,0,0,0,0,0};
        if (!(ks == 1 && lhi >= 2))   // d >= 48 is K-pad
          t = *(const short8*)(smem + offE + (h * 48 + m * 16 + llo) * 96 + ks * 64 + lhi * 16);
        af[m] = t;
      }
      #pragma unroll
      for (int nt = 0; nt < 4; ++nt) {
        const int n = nt * 16 + llo;
        short8 bf8 = *(const short8*)(smem + offV + n * 816 + h * 96 + ks * 64 + lhi * 16);
        #pragma unroll
        for (int m = 0; m < 3; ++m)
          oacc[m][nt] = __builtin_amdgcn_mfma_f32_16x16x32_bf16(af[m], bf8, oacc[m][nt], 0, 0, 0);
      }
    }
    #pragma unroll
    for (int m = 0; m < 3; ++m)
      #pragma unroll
      for (int nt = 0; nt < 4; ++nt) {
        const int n = nt * 16 + llo;
        if (n >= 49) continue;
        const int o0 = h * 48 + m * 16 + lhi * 4;
        char* p = smem + offA + n * 784 + o0 * 2;
        short4v vl = *(short4v*)p;
        short4v ot;
        #pragma unroll
        for (int r = 0; r < 4; ++r) {
          float t = bf2f((unsigned short)vl[r]) + oacc[m][nt][r];
          ot[r] = (short)f2bf(fmaxf(t, 0.f));
        }
        *(short4v*)p = ot;
      }
  }
  __syncthreads();

  // ---- phase 7: P GEMM: out = relu_buf @ Wp^T + bp --------------------------
  {
    f32x4 acc[4][3] = {};
    for (int ks = 0; ks < 12; ++ks) {
      short8 a[4];
      #pragma unroll
      for (int m = 0; m < 4; ++m) {
        int row = m * 16 + llo; row = (row > 48) ? 48 : row;
        a[m] = *(const short8*)(smem + offA + row * 784 + ks * 64 + lhi * 16);
      }
      #pragma unroll
      for (int n = 0; n < 3; ++n) {
        const int o = (w * 3 + n) * 16 + llo;
        short8 bfr = *(const short8*)(Wp_bf + o * 384 + ks * 32 + lhi * 8);
        #pragma unroll
        for (int m = 0; m < 4; ++m)
          acc[m][n] = __builtin_amdgcn_mfma_f32_16x16x32_bf16(a[m], bfr, acc[m][n], 0, 0, 0);
      }
    }
    float* ob = out + (size_t)b * (NPOS * DIMC);
    #pragma unroll
    for (int n = 0; n < 3; ++n) {
      const int o = (w * 3 + n) * 16 + llo;
      const float bias = bp[o];
      #pragma unroll
      for (int m = 0; m < 4; ++m)
        #pragma unroll
        for (int r = 0; r < 4; ++r) {
          int np = m * 16 + lhi * 4 + r;
          if (np < 49) ob[np * 384 + o] = acc[m][n][r] + bias;
        }
    }
  }
}

extern "C" void kernel_launch(void* const* d_in, const int* in_sizes, int n_in,
                              void* d_out, int out_size, void* d_ws, size_t ws_size,
                              hipStream_t stream) {
  const float* x    = (const float*)d_in[0];
  const float* Wq   = (const float*)d_in[1];
  const float* bq   = (const float*)d_in[2];
  const float* Wk   = (const float*)d_in[3];
  const float* bk   = (const float*)d_in[4];
  const float* Wv   = (const float*)d_in[5];
  const float* bv   = (const float*)d_in[6];
  const float* Wvl  = (const float*)d_in[7];
  const float* bvl  = (const float*)d_in[8];
  const float* Wth1 = (const float*)d_in[9];
  const float* bth1 = (const float*)d_in[10];
  const float* Wth2 = (const float*)d_in[11];
  const float* bth2 = (const float*)d_in[12];
  const float* Wp   = (const float*)d_in[13];
  const float* bp   = (const float*)d_in[14];
  unsigned short* Wbf = (unsigned short*)d_ws;   // 1.18 MB of scratch used
  float* out = (float*)d_out;

  hipLaunchKernelGGL(wconv_kernel, dim3(2304), dim3(256), 0, stream,
                     Wq, Wk, Wv, Wp, Wbf);
  hipLaunchKernelGGL(attn_fused_kernel, dim3(2048), dim3(512), LDS_BYTES, stream,
                     x, bq, bk, bv, Wvl, bvl, Wth1, bth1, Wth2, bth2, bp, Wbf, out);
}

// Round 3
// 410.621 us; speedup vs baseline: 1.2218x; 1.2218x over previous
//
#include <hip/hip_runtime.h>
#include <hip/hip_bf16.h>

// ---------------------------------------------------------------------------
// Fused XCiT-style channel attention, one batch item per 512-thread block.
// B=2048, N=49 (7x7), DIM=384, HEADS=8, HD=48.
// R2: fix K-pad zeroing (strided loop over all 768 Qt/Kt rows; R1 only
// covered 512 with a single if, leaving Kt rows 128..383 pads stale).
// ---------------------------------------------------------------------------

typedef __attribute__((ext_vector_type(8))) short short8;   // 8 x bf16 (4 VGPR)
typedef __attribute__((ext_vector_type(4))) short short4v;  // 4 x bf16 (8B)
typedef __attribute__((ext_vector_type(4))) float f32x4;    // MFMA acc

#define NPOS   49
#define DIMC   384
#define SCALE_QK 0.14433756729740643f   // 48^-0.5

// LDS layout (bytes). Total 161296 <= 163840.
//  offA: X bf16 [49][392] (stride 784B) -> later reused as R (relu buffer)
//  offQ: Qt bf16 [384][56] (stride 112B)   } later overlaid by
//  offK: Kt bf16 [384][56]                 } Vn bf16 [64][408] (stride 816B) @ offQ
//  offE: E  bf16 [8][48][48] (row stride 96B)
#define offA 0
#define offQ 38416
#define offK 81424
#define offV 38416
#define offE 124432
#define LDS_BYTES 161296

__device__ __forceinline__ unsigned short f2bf(float f) {
  union { float f; unsigned u; } v; v.f = f;
  unsigned r = v.u + 0x7FFFu + ((v.u >> 16) & 1u);
  return (unsigned short)(r >> 16);
}
__device__ __forceinline__ float bf2f(unsigned short u) {
  union { unsigned u; float f; } v; v.u = ((unsigned)u) << 16;
  return v.f;
}

// ---- prologue: permute Wq,Wk,Wv,Wp (f32 [384][384]) into lane-ordered bf16
// fragment chunks: dst[((g*24+nt)*12+ks)*512 + l*8 + j] =
//   bf16( Wg[nt*16 + (l&15)][ks*32 + (l>>4)*8 + j] )
// so a wave's B-fragment load for (nt,ks) is ONE coalesced 1KB dwordx4 load.
__global__ void wconv_kernel(const float* __restrict__ Wq, const float* __restrict__ Wk,
                             const float* __restrict__ Wv, const float* __restrict__ Wp,
                             unsigned short* __restrict__ dst) {
  int t = blockIdx.x * 256 + threadIdx.x;
  if (t >= 73728) return;            // 4 gemms * 24 nt * 12 ks * 64 lanes
  int l = t & 63;
  int u = t >> 6;
  int ks = u % 12; u /= 12;
  int nt = u % 24;
  int g  = u / 24;
  const float* s = (g == 0) ? Wq : (g == 1) ? Wk : (g == 2) ? Wv : Wp;
  int row = nt * 16 + (l & 15);
  int col = ks * 32 + (l >> 4) * 8;
  const float* sp = s + row * 384 + col;
  short8 o8;
  #pragma unroll
  for (int j = 0; j < 8; ++j) o8[j] = (short)f2bf(sp[j]);
  *(short8*)(dst + (size_t)t * 8) = o8;
}

// ---- main fused kernel -----------------------------------------------------
__global__ __launch_bounds__(512, 2) void attn_fused_kernel(
    const float* __restrict__ x,
    const float* __restrict__ bq, const float* __restrict__ bk,
    const float* __restrict__ bv,
    const float* __restrict__ Wvl, const float* __restrict__ bvl,
    const float* __restrict__ Wth1, const float* __restrict__ bth1,
    const float* __restrict__ Wth2, const float* __restrict__ bth2,
    const float* __restrict__ bp,
    const unsigned short* __restrict__ Wbf,
    float* __restrict__ out) {
  extern __shared__ char smem[];
  const int tid = threadIdx.x;
  const int l   = tid & 63;
  const int w   = tid >> 6;          // wave 0..7
  const int lhi = l >> 4;            // 0..3
  const int llo = l & 15;
  const int b   = blockIdx.x;

  const float* xb = x + (size_t)b * (NPOS * DIMC);
  const unsigned short* Wq_p = Wbf;                // permuted fragment chunks
  const unsigned short* Wk_p = Wbf + 147456;
  const unsigned short* Wv_p = Wbf + 294912;
  const unsigned short* Wp_p = Wbf + 442368;

  // ---- phase 0: stage x_b -> X bf16 [49][392]; zero Qt/Kt pad cols 48..55 ---
  for (int idx = tid; idx < 49 * 48; idx += 512) {
    int row = idx / 48, c8 = idx % 48;
    const float4 v0 = *(const float4*)(xb + row * 384 + c8 * 8);
    const float4 v1 = *(const float4*)(xb + row * 384 + c8 * 8 + 4);
    short8 s;
    s[0] = (short)f2bf(v0.x); s[1] = (short)f2bf(v0.y);
    s[2] = (short)f2bf(v0.z); s[3] = (short)f2bf(v0.w);
    s[4] = (short)f2bf(v1.x); s[5] = (short)f2bf(v1.y);
    s[6] = (short)f2bf(v1.z); s[7] = (short)f2bf(v1.w);
    *(short8*)(smem + offA + row * 784 + c8 * 16) = s;
  }
  // zero bytes 96..111 (cols 48..55) of EVERY Qt/Kt row (768 rows, 512 thr)
  for (int r2 = tid; r2 < 768; r2 += 512) {
    char* base = smem + ((r2 < 384) ? offQ : offK) + (r2 & 383) * 112;
    short8 z = {0,0,0,0,0,0,0,0};
    *(short8*)(base + 96) = z;
  }
  __syncthreads();

  // ---- phase 1: Q GEMM (waves 0-3) / K GEMM (waves 4-7) --------------------
  // epilogue: in-register L2 norm over positions (per-lane masked ss +
  // shfl_xor over lhi groups), then transposed normalized store.
  {
    const int wq = w & 3;
    const unsigned short* Wg = (w < 4) ? Wq_p : Wk_p;
    const float* bg          = (w < 4) ? bq   : bk;
    char* dst = smem + ((w < 4) ? offQ : offK);
    f32x4 acc[4][6] = {};
    for (int ks = 0; ks < 12; ++ks) {
      short8 a[4];
      #pragma unroll
      for (int m = 0; m < 4; ++m) {
        int row = m * 16 + llo; row = (row > 48) ? 48 : row;   // M-pad clamp
        a[m] = *(const short8*)(smem + offA + row * 784 + ks * 64 + lhi * 16);
      }
      #pragma unroll
      for (int n = 0; n < 6; ++n) {
        const int nt = wq * 6 + n;
        short8 bfr = *(const short8*)(Wg + ((nt * 12 + ks) << 9) + (l << 3));
        #pragma unroll
        for (int m = 0; m < 4; ++m)
          acc[m][n] = __builtin_amdgcn_mfma_f32_16x16x32_bf16(a[m], bfr, acc[m][n], 0, 0, 0);
      }
    }
    #pragma unroll
    for (int n = 0; n < 6; ++n) {
      const int o = (wq * 6 + n) * 16 + llo;
      const float bias = bg[o];
      float ss = 0.f;
      #pragma unroll
      for (int m = 0; m < 4; ++m)
        #pragma unroll
        for (int r = 0; r < 4; ++r) {
          acc[m][n][r] += bias;
          int np = m * 16 + lhi * 4 + r;
          if (np < 49) ss += acc[m][n][r] * acc[m][n][r];
        }
      ss += __shfl_xor(ss, 16, 64);
      ss += __shfl_xor(ss, 32, 64);
      const float sc = 1.f / fmaxf(sqrtf(ss), 1e-12f);
      #pragma unroll
      for (int m = 0; m < 4; ++m) {
        const int n0 = m * 16 + lhi * 4;          // position index of acc[..][0]
        if (n0 > 48) continue;
        if (n0 == 48) {
          *(unsigned short*)(dst + o * 112 + 96) = f2bf(acc[m][n][0] * sc);
        } else {
          short4v pk;
          pk[0] = (short)f2bf(acc[m][n][0] * sc);
          pk[1] = (short)f2bf(acc[m][n][1] * sc);
          pk[2] = (short)f2bf(acc[m][n][2] * sc);
          pk[3] = (short)f2bf(acc[m][n][3] * sc);
          *(short4v*)(dst + o * 112 + n0 * 2) = pk;
        }
      }
    }
  }
  __syncthreads();

  // ---- phase 3: per-head gram G[c][d] = sum_n q~[c][n] k~[d][n] (head = w) --
  {
    const int h = w;
    f32x4 g[3][3] = {};
    #pragma unroll
    for (int ks = 0; ks < 2; ++ks) {
      short8 aq[3], bk8[3];
      #pragma unroll
      for (int m = 0; m < 3; ++m) {
        short8 t = {0,0,0,0,0,0,0,0};
        if (!(ks == 1 && lhi == 3))  // n=56..63 do not exist
          t = *(const short8*)(smem + offQ + (h * 48 + m * 16 + llo) * 112 + ks * 64 + lhi * 16);
        aq[m] = t;
      }
      #pragma unroll
      for (int n = 0; n < 3; ++n) {
        short8 t = {0,0,0,0,0,0,0,0};
        if (!(ks == 1 && lhi == 3))
          t = *(const short8*)(smem + offK + (h * 48 + n * 16 + llo) * 112 + ks * 64 + lhi * 16);
        bk8[n] = t;
      }
      #pragma unroll
      for (int m = 0; m < 3; ++m)
        #pragma unroll
        for (int n = 0; n < 3; ++n)
          g[m][n] = __builtin_amdgcn_mfma_f32_16x16x32_bf16(aq[m], bk8[n], g[m][n], 0, 0, 0);
    }
    #pragma unroll
    for (int m = 0; m < 3; ++m)
      #pragma unroll
      for (int n = 0; n < 3; ++n)
        #pragma unroll
        for (int r = 0; r < 4; ++r) {
          int c = m * 16 + lhi * 4 + r, d = n * 16 + llo;
          *(unsigned short*)(smem + offE + ((h * 48 + c) * 48 + d) * 2) = f2bf(g[m][n][r]);
        }
  }
  __syncthreads();

  // ---- phase 4: talking-heads mix1 (SCALE folded into W1), in-place on E ----
  {
    float w1[64], b1r[8];
    #pragma unroll
    for (int i = 0; i < 64; ++i) w1[i] = Wth1[i] * SCALE_QK;
    #pragma unroll
    for (int i = 0; i < 8; ++i) b1r[i] = bth1[i];
    for (int s = tid; s < 2304; s += 512) {
      char* base = smem + offE + s * 2;   // s = c*48+d
      float gg[8];
      #pragma unroll
      for (int hh = 0; hh < 8; ++hh) gg[hh] = bf2f(*(unsigned short*)(base + hh * 4608));
      #pragma unroll
      for (int gdx = 0; gdx < 8; ++gdx) {
        float t = b1r[gdx];
        #pragma unroll
        for (int hh = 0; hh < 8; ++hh) t += gg[hh] * w1[gdx * 8 + hh];
        *(unsigned short*)(base + gdx * 4608) = f2bf(t);
      }
    }
  }
  __syncthreads();

  // ---- phase 4b: row softmax over d (rows = (g,c), 384 of them) -------------
  for (int row = tid; row < 384; row += 512) {
    char* rp = smem + offE + row * 96;
    float vv[48];
    #pragma unroll
    for (int i = 0; i < 6; ++i) {
      short8 v8 = *(short8*)(rp + i * 16);
      #pragma unroll
      for (int j = 0; j < 8; ++j) vv[i * 8 + j] = bf2f((unsigned short)v8[j]);
    }
    float mx = vv[0];
    #pragma unroll
    for (int i = 1; i < 48; ++i) mx = fmaxf(mx, vv[i]);
    float sum = 0.f;
    #pragma unroll
    for (int i = 0; i < 48; ++i) { vv[i] = __expf(vv[i] - mx); sum += vv[i]; }
    float inv = 1.f / sum;
    #pragma unroll
    for (int i = 0; i < 6; ++i) {
      short8 o8;
      #pragma unroll
      for (int j = 0; j < 8; ++j) o8[j] = (short)f2bf(vv[i * 8 + j] * inv);
      *(short8*)(rp + i * 16) = o8;
    }
  }
  __syncthreads();

  // ---- phase 4c: talking-heads mix2, in-place on E --------------------------
  {
    float w2[64], b2r[8];
    #pragma unroll
    for (int i = 0; i < 64; ++i) w2[i] = Wth2[i];
    #pragma unroll
    for (int i = 0; i < 8; ++i) b2r[i] = bth2[i];
    for (int s = tid; s < 2304; s += 512) {
      char* base = smem + offE + s * 2;
      float gg[8];
      #pragma unroll
      for (int hh = 0; hh < 8; ++hh) gg[hh] = bf2f(*(unsigned short*)(base + hh * 4608));
      #pragma unroll
      for (int gdx = 0; gdx < 8; ++gdx) {
        float t = b2r[gdx];
        #pragma unroll
        for (int hh = 0; hh < 8; ++hh) t += gg[hh] * w2[gdx * 8 + hh];
        *(unsigned short*)(base + gdx * 4608) = f2bf(t);
      }
    }
  }
  __syncthreads();

  // ---- phase 5: V GEMM -> Vn natural [64][408] (overlays dead Qt/Kt) --------
  {
    f32x4 acc[4][3] = {};
    for (int ks = 0; ks < 12; ++ks) {
      short8 a[4];
      #pragma unroll
      for (int m = 0; m < 4; ++m) {
        int row = m * 16 + llo; row = (row > 48) ? 48 : row;
        a[m] = *(const short8*)(smem + offA + row * 784 + ks * 64 + lhi * 16);
      }
      #pragma unroll
      for (int n = 0; n < 3; ++n) {
        const int nt = w * 3 + n;
        short8 bfr = *(const short8*)(Wv_p + ((nt * 12 + ks) << 9) + (l << 3));
        #pragma unroll
        for (int m = 0; m < 4; ++m)
          acc[m][n] = __builtin_amdgcn_mfma_f32_16x16x32_bf16(a[m], bfr, acc[m][n], 0, 0, 0);
      }
    }
    #pragma unroll
    for (int n = 0; n < 3; ++n) {
      const int o = (w * 3 + n) * 16 + llo;
      const float bias = bv[o];
      #pragma unroll
      for (int m = 0; m < 4; ++m)
        #pragma unroll
        for (int r = 0; r < 4; ++r) {
          int np = m * 16 + lhi * 4 + r;
          if (np < 49)
            *(unsigned short*)(smem + offV + np * 816 + o * 2) = f2bf(acc[m][n][r] + bias);
        }
    }
    // zero pads: rows 49..63 (all 408 cols) and cols 384..407 (rows 0..48)
    for (int idx = tid; idx < 7296; idx += 512) {
      int row, col;
      if (idx < 6120) { row = 49 + idx / 408; col = idx % 408; }
      else            { int j2 = idx - 6120; row = j2 / 24; col = 384 + j2 % 24; }
      *(unsigned short*)(smem + offV + row * 816 + col * 2) = 0;
    }
  }
  __syncthreads();

  // ---- phase 6a: depthwise 3x3 + bvl -> R [49][392] (overlays dead X) -------
  for (int idx = tid; idx < 2352; idx += 512) {
    int n = idx / 48, c8 = idx % 48;
    int o0 = c8 * 8;
    int y = n / 7, xq = n % 7;
    float a[8];
    #pragma unroll
    for (int j = 0; j < 8; ++j) a[j] = bvl[o0 + j];
    #pragma unroll
    for (int dy = 0; dy < 3; ++dy) {
      int yy = y + dy - 1;
      if (yy < 0 || yy > 6) continue;
      #pragma unroll
      for (int dx = 0; dx < 3; ++dx) {
        int xx = xq + dx - 1;
        if (xx < 0 || xx > 6) continue;
        short8 vv = *(const short8*)(smem + offV + (yy * 7 + xx) * 816 + o0 * 2);
        const float* wp = Wvl + (dy * 3 + dx) * 384 + o0;
        #pragma unroll
        for (int j = 0; j < 8; ++j) a[j] += bf2f((unsigned short)vv[j]) * wp[j];
      }
    }
    short8 s8;
    #pragma unroll
    for (int j = 0; j < 8; ++j) s8[j] = (short)f2bf(a[j]);
    *(short8*)(smem + offA + n * 784 + c8 * 16) = s8;
  }
  __syncthreads();

  // ---- phase 6b: AV per head (head = w); RMW R with +v_local, fused ReLU ----
  {
    const int h = w;
    f32x4 oacc[3][4] = {};
    #pragma unroll
    for (int ks = 0; ks < 2; ++ks) {
      short8 af[3];
      #pragma unroll
      for (int m = 0; m < 3; ++m) {
        short8 t = {0,0,0,0,0,0,0,0};
        if (!(ks == 1 && lhi >= 2))   // d >= 48 is K-pad
          t = *(const short8*)(smem + offE + (h * 48 + m * 16 + llo) * 96 + ks * 64 + lhi * 16);
        af[m] = t;
      }
      #pragma unroll
      for (int nt = 0; nt < 4; ++nt) {
        const int n = nt * 16 + llo;
        short8 bf8 = *(const short8*)(smem + offV + n * 816 + h * 96 + ks * 64 + lhi * 16);
        #pragma unroll
        for (int m = 0; m < 3; ++m)
          oacc[m][nt] = __builtin_amdgcn_mfma_f32_16x16x32_bf16(af[m], bf8, oacc[m][nt], 0, 0, 0);
      }
    }
    #pragma unroll
    for (int m = 0; m < 3; ++m)
      #pragma unroll
      for (int nt = 0; nt < 4; ++nt) {
        const int n = nt * 16 + llo;
        if (n >= 49) continue;
        const int o0 = h * 48 + m * 16 + lhi * 4;
        char* p = smem + offA + n * 784 + o0 * 2;
        short4v vl = *(short4v*)p;
        short4v ot;
        #pragma unroll
        for (int r = 0; r < 4; ++r) {
          float t = bf2f((unsigned short)vl[r]) + oacc[m][nt][r];
          ot[r] = (short)f2bf(fmaxf(t, 0.f));
        }
        *(short4v*)p = ot;
      }
  }
  __syncthreads();

  // ---- phase 7: P GEMM: out = relu_buf @ Wp^T + bp --------------------------
  {
    f32x4 acc[4][3] = {};
    for (int ks = 0; ks < 12; ++ks) {
      short8 a[4];
      #pragma unroll
      for (int m = 0; m < 4; ++m) {
        int row = m * 16 + llo; row = (row > 48) ? 48 : row;
        a[m] = *(const short8*)(smem + offA + row * 784 + ks * 64 + lhi * 16);
      }
      #pragma unroll
      for (int n = 0; n < 3; ++n) {
        const int nt = w * 3 + n;
        short8 bfr = *(const short8*)(Wp_p + ((nt * 12 + ks) << 9) + (l << 3));
        #pragma unroll
        for (int m = 0; m < 4; ++m)
          acc[m][n] = __builtin_amdgcn_mfma_f32_16x16x32_bf16(a[m], bfr, acc[m][n], 0, 0, 0);
      }
    }
    float* ob = out + (size_t)b * (NPOS * DIMC);
    #pragma unroll
    for (int n = 0; n < 3; ++n) {
      const int o = (w * 3 + n) * 16 + llo;
      const float bias = bp[o];
      #pragma unroll
      for (int m = 0; m < 4; ++m)
        #pragma unroll
        for (int r = 0; r < 4; ++r) {
          int np = m * 16 + lhi * 4 + r;
          if (np < 49) ob[np * 384 + o] = acc[m][n][r] + bias;
        }
    }
  }
}

extern "C" void kernel_launch(void* const* d_in, const int* in_sizes, int n_in,
                              void* d_out, int out_size, void* d_ws, size_t ws_size,
                              hipStream_t stream) {
  const float* x    = (const float*)d_in[0];
  const float* Wq   = (const float*)d_in[1];
  const float* bq   = (const float*)d_in[2];
  const float* Wk   = (const float*)d_in[3];
  const float* bk   = (const float*)d_in[4];
  const float* Wv   = (const float*)d_in[5];
  const float* bv   = (const float*)d_in[6];
  const float* Wvl  = (const float*)d_in[7];
  const float* bvl  = (const float*)d_in[8];
  const float* Wth1 = (const float*)d_in[9];
  const float* bth1 = (const float*)d_in[10];
  const float* Wth2 = (const float*)d_in[11];
  const float* bth2 = (const float*)d_in[12];
  const float* Wp   = (const float*)d_in[13];
  const float* bp   = (const float*)d_in[14];
  unsigned short* Wbf = (unsigned short*)d_ws;   // 1.18 MB of scratch used
  float* out = (float*)d_out;

  hipLaunchKernelGGL(wconv_kernel, dim3(288), dim3(256), 0, stream,
                     Wq, Wk, Wv, Wp, Wbf);
  hipLaunchKernelGGL(attn_fused_kernel, dim3(2048), dim3(512), LDS_BYTES, stream,
                     x, bq, bk, bv, Wvl, bvl, Wth1, bth1, Wth2, bth2, bp, Wbf, out);
}

// Round 5
// 405.866 us; speedup vs baseline: 1.2361x; 1.0117x over previous
//
#include <hip/hip_runtime.h>
#include <hip/hip_bf16.h>

// ---------------------------------------------------------------------------
// Fused XCiT-style channel attention, one batch item per 512-thread block.
// B=2048, N=49 (7x7), DIM=384, HEADS=8, HD=48.
// R5: R4 (wave-owns-head merged QKV GEMM, reg-held V, no Vn zero-fill)
// + barrier between Qt/Kt stores and gram reads (R4 relied on intra-wave
// LDS ordering; compiler reordered the aliased ds accesses -> R2-identical
// stale-pad failure) + AV B-frag masked at ks==1&&lhi>=2 (NaN-safety for
// unwritten Vn pad columns). Barriers: 8 (was 10 in R3).
// ---------------------------------------------------------------------------

typedef __attribute__((ext_vector_type(8))) short short8;   // 8 x bf16 (4 VGPR)
typedef __attribute__((ext_vector_type(4))) short short4v;  // 4 x bf16 (8B)
typedef __attribute__((ext_vector_type(4))) float f32x4;    // MFMA acc

#define NPOS   49
#define DIMC   384
#define SCALE_QK 0.14433756729740643f   // 48^-0.5

// LDS layout (bytes). Total 161296 <= 163840.
//  offA: X bf16 [49][392] (stride 784B) -> later reused as R (relu buffer)
//  offQ: Qt bf16 [384][56] (stride 112B)   } after gram, overlaid by
//  offK: Kt bf16 [384][56]                 } Vn bf16 [64][408] (stride 816B)
//  offE: E  bf16 [8][48][48] (row stride 96B)
#define offA 0
#define offQ 38416
#define offK 81424
#define offV 38416
#define offE 124432
#define LDS_BYTES 161296

__device__ __forceinline__ unsigned short f2bf(float f) {
  __hip_bfloat16 h = __float2bfloat16(f);
  unsigned short u;
  __builtin_memcpy(&u, &h, 2);
  return u;
}
__device__ __forceinline__ float bf2f(unsigned short u) {
  union { unsigned u; float f; } v; v.u = ((unsigned)u) << 16;
  return v.f;
}

// ---- prologue: permute Wq,Wk,Wv,Wp (f32 [384][384]) into lane-ordered bf16
// fragment chunks: dst[((g*24+nt)*12+ks)*512 + l*8 + j] =
//   bf16( Wg[nt*16 + (l&15)][ks*32 + (l>>4)*8 + j] )
__global__ void wconv_kernel(const float* __restrict__ Wq, const float* __restrict__ Wk,
                             const float* __restrict__ Wv, const float* __restrict__ Wp,
                             unsigned short* __restrict__ dst) {
  int t = blockIdx.x * 256 + threadIdx.x;
  if (t >= 73728) return;            // 4 gemms * 24 nt * 12 ks * 64 lanes
  int l = t & 63;
  int u = t >> 6;
  int ks = u % 12; u /= 12;
  int nt = u % 24;
  int g  = u / 24;
  const float* s = (g == 0) ? Wq : (g == 1) ? Wk : (g == 2) ? Wv : Wp;
  int row = nt * 16 + (l & 15);
  int col = ks * 32 + (l >> 4) * 8;
  const float* sp = s + row * 384 + col;
  short8 o8;
  #pragma unroll
  for (int j = 0; j < 8; ++j) o8[j] = (short)f2bf(sp[j]);
  *(short8*)(dst + (size_t)t * 8) = o8;
}

// ---- main fused kernel -----------------------------------------------------
__global__ __launch_bounds__(512, 2) void attn_fused_kernel(
    const float* __restrict__ x,
    const float* __restrict__ bq, const float* __restrict__ bk,
    const float* __restrict__ bv,
    const float* __restrict__ Wvl, const float* __restrict__ bvl,
    const float* __restrict__ Wth1, const float* __restrict__ bth1,
    const float* __restrict__ Wth2, const float* __restrict__ bth2,
    const float* __restrict__ bp,
    const unsigned short* __restrict__ Wbf,
    float* __restrict__ out) {
  extern __shared__ char smem[];
  const int tid = threadIdx.x;
  const int l   = tid & 63;
  const int w   = tid >> 6;          // wave 0..7 == head h
  const int lhi = l >> 4;            // 0..3
  const int llo = l & 15;
  const int b   = blockIdx.x;

  const float* xb = x + (size_t)b * (NPOS * DIMC);
  const unsigned short* Wq_p = Wbf;                // permuted fragment chunks
  const unsigned short* Wk_p = Wbf + 147456;
  const unsigned short* Wv_p = Wbf + 294912;
  const unsigned short* Wp_p = Wbf + 442368;

  // ---- phase 0: stage x_b -> X bf16 [49][392]; zero Qt/Kt pad cols 48..55 ---
  for (int idx = tid; idx < 49 * 48; idx += 512) {
    int row = idx / 48, c8 = idx % 48;
    const float4 v0 = *(const float4*)(xb + row * 384 + c8 * 8);
    const float4 v1 = *(const float4*)(xb + row * 384 + c8 * 8 + 4);
    short8 s;
    s[0] = (short)f2bf(v0.x); s[1] = (short)f2bf(v0.y);
    s[2] = (short)f2bf(v0.z); s[3] = (short)f2bf(v0.w);
    s[4] = (short)f2bf(v1.x); s[5] = (short)f2bf(v1.y);
    s[6] = (short)f2bf(v1.z); s[7] = (short)f2bf(v1.w);
    *(short8*)(smem + offA + row * 784 + c8 * 16) = s;
  }
  for (int r2 = tid; r2 < 768; r2 += 512) {
    char* base = smem + ((r2 < 384) ? offQ : offK) + (r2 & 383) * 112;
    short8 z = {0,0,0,0,0,0,0,0};
    *(short8*)(base + 96) = z;
  }
  __syncthreads();

  // ---- MEGA-GEMM: Q,K,V for head w (A-frags shared by 9 B-tiles) -----------
  f32x4 aV[4][3] = {};               // V acc survives until post-barrier store
  {
    f32x4 aQ[4][3] = {}, aK[4][3] = {};
    for (int ks = 0; ks < 12; ++ks) {
      short8 a[4];
      #pragma unroll
      for (int m = 0; m < 4; ++m) {
        int row = m * 16 + llo; row = (row > 48) ? 48 : row;   // M-pad clamp
        a[m] = *(const short8*)(smem + offA + row * 784 + ks * 64 + lhi * 16);
      }
      #pragma unroll
      for (int n = 0; n < 3; ++n) {
        const int nt = w * 3 + n;
        short8 bq8 = *(const short8*)(Wq_p + ((nt * 12 + ks) << 9) + (l << 3));
        short8 bk8 = *(const short8*)(Wk_p + ((nt * 12 + ks) << 9) + (l << 3));
        short8 bv8 = *(const short8*)(Wv_p + ((nt * 12 + ks) << 9) + (l << 3));
        #pragma unroll
        for (int m = 0; m < 4; ++m) {
          aQ[m][n] = __builtin_amdgcn_mfma_f32_16x16x32_bf16(a[m], bq8, aQ[m][n], 0, 0, 0);
          aK[m][n] = __builtin_amdgcn_mfma_f32_16x16x32_bf16(a[m], bk8, aK[m][n], 0, 0, 0);
          aV[m][n] = __builtin_amdgcn_mfma_f32_16x16x32_bf16(a[m], bv8, aV[m][n], 0, 0, 0);
        }
      }
    }
    // ---- epilogue: bias + in-register L2 norm + transposed store (Q then K) -
    #pragma unroll
    for (int qk = 0; qk < 2; ++qk) {
      f32x4 (*acc)[3] = qk ? aK : aQ;
      const float* bg = qk ? bk : bq;
      char* dst = smem + (qk ? offK : offQ);
      #pragma unroll
      for (int n = 0; n < 3; ++n) {
        const int o = (w * 3 + n) * 16 + llo;
        const float bias = bg[o];
        float ss = 0.f;
        #pragma unroll
        for (int m = 0; m < 4; ++m)
          #pragma unroll
          for (int r = 0; r < 4; ++r) {
            acc[m][n][r] += bias;
            int np = m * 16 + lhi * 4 + r;
            if (np < 49) ss += acc[m][n][r] * acc[m][n][r];
          }
        ss += __shfl_xor(ss, 16, 64);
        ss += __shfl_xor(ss, 32, 64);
        const float sc = 1.f / fmaxf(sqrtf(ss), 1e-12f);
        #pragma unroll
        for (int m = 0; m < 4; ++m) {
          const int n0 = m * 16 + lhi * 4;
          if (n0 > 48) continue;
          if (n0 == 48) {
            *(unsigned short*)(dst + o * 112 + 96) = f2bf(acc[m][n][0] * sc);
          } else {
            short4v pk;
            pk[0] = (short)f2bf(acc[m][n][0] * sc);
            pk[1] = (short)f2bf(acc[m][n][1] * sc);
            pk[2] = (short)f2bf(acc[m][n][2] * sc);
            pk[3] = (short)f2bf(acc[m][n][3] * sc);
            *(short4v*)(dst + o * 112 + n0 * 2) = pk;
          }
        }
      }
    }
  }
  // Qt/Kt stores must be visible before gram reads. R4 relied on intra-wave
  // LDS ordering; the compiler reordered the aliased accesses. Hard barrier.
  __syncthreads();

  // ---- gram for head w: G[c][d] = sum_n q~[c][n] k~[d][n] -------------------
  {
    const int h = w;
    f32x4 g[3][3] = {};
    #pragma unroll
    for (int ks = 0; ks < 2; ++ks) {
      short8 aq[3], bk8[3];
      #pragma unroll
      for (int m = 0; m < 3; ++m) {
        short8 t = {0,0,0,0,0,0,0,0};
        if (!(ks == 1 && lhi == 3))  // n=56..63 do not exist
          t = *(const short8*)(smem + offQ + (h * 48 + m * 16 + llo) * 112 + ks * 64 + lhi * 16);
        aq[m] = t;
      }
      #pragma unroll
      for (int n = 0; n < 3; ++n) {
        short8 t = {0,0,0,0,0,0,0,0};
        if (!(ks == 1 && lhi == 3))
          t = *(const short8*)(smem + offK + (h * 48 + n * 16 + llo) * 112 + ks * 64 + lhi * 16);
        bk8[n] = t;
      }
      #pragma unroll
      for (int m = 0; m < 3; ++m)
        #pragma unroll
        for (int n = 0; n < 3; ++n)
          g[m][n] = __builtin_amdgcn_mfma_f32_16x16x32_bf16(aq[m], bk8[n], g[m][n], 0, 0, 0);
    }
    #pragma unroll
    for (int m = 0; m < 3; ++m)
      #pragma unroll
      for (int n = 0; n < 3; ++n)
        #pragma unroll
        for (int r = 0; r < 4; ++r) {
          int c = m * 16 + lhi * 4 + r, d = n * 16 + llo;
          *(unsigned short*)(smem + offE + ((h * 48 + c) * 48 + d) * 2) = f2bf(g[m][n][r]);
        }
  }
  __syncthreads();   // E complete; all Qt/Kt reads done (Vn may now overlay)

  // ---- V-store (from regs, overlays dead Qt/Kt) + talking-heads mix1 -------
  {
    #pragma unroll
    for (int n = 0; n < 3; ++n) {
      const int o = (w * 3 + n) * 16 + llo;
      const float bias = bv[o];
      #pragma unroll
      for (int m = 0; m < 4; ++m)
        #pragma unroll
        for (int r = 0; r < 4; ++r) {
          int np = m * 16 + lhi * 4 + r;
          if (np < 49)
            *(unsigned short*)(smem + offV + np * 816 + o * 2) = f2bf(aV[m][n][r] + bias);
        }
    }
    // NOTE: no Vn zero-fill. Pos rows 49..63 feed only discarded output cols;
    // ch pads are never read (AV B-frag masked at ks==1&&lhi>=2).
  }
  {
    float w1[64], b1r[8];
    #pragma unroll
    for (int i = 0; i < 64; ++i) w1[i] = Wth1[i] * SCALE_QK;
    #pragma unroll
    for (int i = 0; i < 8; ++i) b1r[i] = bth1[i];
    for (int s = tid; s < 2304; s += 512) {
      char* base = smem + offE + s * 2;   // s = c*48+d
      float gg[8];
      #pragma unroll
      for (int hh = 0; hh < 8; ++hh) gg[hh] = bf2f(*(unsigned short*)(base + hh * 4608));
      #pragma unroll
      for (int gdx = 0; gdx < 8; ++gdx) {
        float t = b1r[gdx];
        #pragma unroll
        for (int hh = 0; hh < 8; ++hh) t += gg[hh] * w1[gdx * 8 + hh];
        *(unsigned short*)(base + gdx * 4608) = f2bf(t);
      }
    }
  }
  __syncthreads();

  // ---- row softmax over d (rows = (g,c), 384 of them) -----------------------
  for (int row = tid; row < 384; row += 512) {
    char* rp = smem + offE + row * 96;
    float vv[48];
    #pragma unroll
    for (int i = 0; i < 6; ++i) {
      short8 v8 = *(short8*)(rp + i * 16);
      #pragma unroll
      for (int j = 0; j < 8; ++j) vv[i * 8 + j] = bf2f((unsigned short)v8[j]);
    }
    float mx = vv[0];
    #pragma unroll
    for (int i = 1; i < 48; ++i) mx = fmaxf(mx, vv[i]);
    float sum = 0.f;
    #pragma unroll
    for (int i = 0; i < 48; ++i) { vv[i] = __expf(vv[i] - mx); sum += vv[i]; }
    float inv = 1.f / sum;
    #pragma unroll
    for (int i = 0; i < 6; ++i) {
      short8 o8;
      #pragma unroll
      for (int j = 0; j < 8; ++j) o8[j] = (short)f2bf(vv[i * 8 + j] * inv);
      *(short8*)(rp + i * 16) = o8;
    }
  }
  __syncthreads();

  // ---- talking-heads mix2, in-place on E ------------------------------------
  {
    float w2[64], b2r[8];
    #pragma unroll
    for (int i = 0; i < 64; ++i) w2[i] = Wth2[i];
    #pragma unroll
    for (int i = 0; i < 8; ++i) b2r[i] = bth2[i];
    for (int s = tid; s < 2304; s += 512) {
      char* base = smem + offE + s * 2;
      float gg[8];
      #pragma unroll
      for (int hh = 0; hh < 8; ++hh) gg[hh] = bf2f(*(unsigned short*)(base + hh * 4608));
      #pragma unroll
      for (int gdx = 0; gdx < 8; ++gdx) {
        float t = b2r[gdx];
        #pragma unroll
        for (int hh = 0; hh < 8; ++hh) t += gg[hh] * w2[gdx * 8 + hh];
        *(unsigned short*)(base + gdx * 4608) = f2bf(t);
      }
    }
  }
  __syncthreads();

  // ---- depthwise 3x3 + bvl -> R [49][392] (overlays dead X) -----------------
  for (int idx = tid; idx < 2352; idx += 512) {
    int n = idx / 48, c8 = idx % 48;
    int o0 = c8 * 8;
    int y = n / 7, xq = n % 7;
    float a[8];
    #pragma unroll
    for (int j = 0; j < 8; ++j) a[j] = bvl[o0 + j];
    #pragma unroll
    for (int dy = 0; dy < 3; ++dy) {
      int yy = y + dy - 1;
      if (yy < 0 || yy > 6) continue;
      #pragma unroll
      for (int dx = 0; dx < 3; ++dx) {
        int xx = xq + dx - 1;
        if (xx < 0 || xx > 6) continue;
        short8 vv = *(const short8*)(smem + offV + (yy * 7 + xx) * 816 + o0 * 2);
        const float* wp = Wvl + (dy * 3 + dx) * 384 + o0;
        #pragma unroll
        for (int j = 0; j < 8; ++j) a[j] += bf2f((unsigned short)vv[j]) * wp[j];
      }
    }
    short8 s8;
    #pragma unroll
    for (int j = 0; j < 8; ++j) s8[j] = (short)f2bf(a[j]);
    *(short8*)(smem + offA + n * 784 + c8 * 16) = s8;
  }
  __syncthreads();

  // ---- AV per head (head = w); RMW R with +v_local, fused ReLU --------------
  {
    const int h = w;
    f32x4 oacc[3][4] = {};
    #pragma unroll
    for (int ks = 0; ks < 2; ++ks) {
      short8 af[3];
      #pragma unroll
      for (int m = 0; m < 3; ++m) {
        short8 t = {0,0,0,0,0,0,0,0};
        if (!(ks == 1 && lhi >= 2))   // d >= 48 is K-pad
          t = *(const short8*)(smem + offE + (h * 48 + m * 16 + llo) * 96 + ks * 64 + lhi * 16);
        af[m] = t;
      }
      #pragma unroll
      for (int nt = 0; nt < 4; ++nt) {
        const int n = nt * 16 + llo;
        short8 bf8 = {0,0,0,0,0,0,0,0};
        if (!(ks == 1 && lhi >= 2))   // matching mask: avoids unwritten Vn pads
          bf8 = *(const short8*)(smem + offV + n * 816 + h * 96 + ks * 64 + lhi * 16);
        #pragma unroll
        for (int m = 0; m < 3; ++m)
          oacc[m][nt] = __builtin_amdgcn_mfma_f32_16x16x32_bf16(af[m], bf8, oacc[m][nt], 0, 0, 0);
      }
    }
    #pragma unroll
    for (int m = 0; m < 3; ++m)
      #pragma unroll
      for (int nt = 0; nt < 4; ++nt) {
        const int n = nt * 16 + llo;
        if (n >= 49) continue;
        const int o0 = h * 48 + m * 16 + lhi * 4;
        char* p = smem + offA + n * 784 + o0 * 2;
        short4v vl = *(short4v*)p;
        short4v ot;
        #pragma unroll
        for (int r = 0; r < 4; ++r) {
          float t = bf2f((unsigned short)vl[r]) + oacc[m][nt][r];
          ot[r] = (short)f2bf(fmaxf(t, 0.f));
        }
        *(short4v*)p = ot;
      }
  }
  __syncthreads();

  // ---- P GEMM: out = relu_buf @ Wp^T + bp -----------------------------------
  {
    f32x4 acc[4][3] = {};
    for (int ks = 0; ks < 12; ++ks) {
      short8 a[4];
      #pragma unroll
      for (int m = 0; m < 4; ++m) {
        int row = m * 16 + llo; row = (row > 48) ? 48 : row;
        a[m] = *(const short8*)(smem + offA + row * 784 + ks * 64 + lhi * 16);
      }
      #pragma unroll
      for (int n = 0; n < 3; ++n) {
        const int nt = w * 3 + n;
        short8 bfr = *(const short8*)(Wp_p + ((nt * 12 + ks) << 9) + (l << 3));
        #pragma unroll
        for (int m = 0; m < 4; ++m)
          acc[m][n] = __builtin_amdgcn_mfma_f32_16x16x32_bf16(a[m], bfr, acc[m][n], 0, 0, 0);
      }
    }
    float* ob = out + (size_t)b * (NPOS * DIMC);
    #pragma unroll
    for (int n = 0; n < 3; ++n) {
      const int o = (w * 3 + n) * 16 + llo;
      const float bias = bp[o];
      #pragma unroll
      for (int m = 0; m < 4; ++m)
        #pragma unroll
        for (int r = 0; r < 4; ++r) {
          int np = m * 16 + lhi * 4 + r;
          if (np < 49) ob[np * 384 + o] = acc[m][n][r] + bias;
        }
    }
  }
}

extern "C" void kernel_launch(void* const* d_in, const int* in_sizes, int n_in,
                              void* d_out, int out_size, void* d_ws, size_t ws_size,
                              hipStream_t stream) {
  const float* x    = (const float*)d_in[0];
  const float* Wq   = (const float*)d_in[1];
  const float* bq   = (const float*)d_in[2];
  const float* Wk   = (const float*)d_in[3];
  const float* bk   = (const float*)d_in[4];
  const float* Wv   = (const float*)d_in[5];
  const float* bv   = (const float*)d_in[6];
  const float* Wvl  = (const float*)d_in[7];
  const float* bvl  = (const float*)d_in[8];
  const float* Wth1 = (const float*)d_in[9];
  const float* bth1 = (const float*)d_in[10];
  const float* Wth2 = (const float*)d_in[11];
  const float* bth2 = (const float*)d_in[12];
  const float* Wp   = (const float*)d_in[13];
  const float* bp   = (const float*)d_in[14];
  unsigned short* Wbf = (unsigned short*)d_ws;   // 1.18 MB of scratch used
  float* out = (float*)d_out;

  hipLaunchKernelGGL(wconv_kernel, dim3(288), dim3(256), 0, stream,
                     Wq, Wk, Wv, Wp, Wbf);
  hipLaunchKernelGGL(attn_fused_kernel, dim3(2048), dim3(512), LDS_BYTES, stream,
                     x, bq, bk, bv, Wvl, bvl, Wth1, bth1, Wth2, bth2, bp, Wbf, out);
}